// Round 12
// baseline (3572.919 us; speedup 1.0000x reference)
//
#include <hip/hip_runtime.h>
#include <hip/hip_bf16.h>

// ByteLevelDecoder: B=2,S=256,H=1024, BH=384,NH=8,HD=48, P=4,S_C=12,L=4,V=258,T=16
// Persistent kernel. Round 20: SPB=4 with the publish-slot COLLISION FIXED.
// Round-18/19's bug: split-K partials were published at loop-local s2, so both
// kg-halves wrote the same qkvp/wop/w2p slots (race -> absmax 9.97). Now the
// slot is ls*NT+tok where ls = block-local index of the seq being published
// (disjoint writer/reader sets in both pass shapes). Buffers flattened to
// [8][BH]; union size unchanged (~61KB); LDS ~156KB.
// Model under test (round-9): per-XCD L2 weight-stream BW bound; 4 seqs/block
// (grid 128, 16/XCD) halves per-XCD weight traffic.

constexpr int H_IN  = 1024;
constexpr int BH    = 384;
constexpr int NH    = 8;
constexpr int HD    = 48;
constexpr int PP    = 4;
constexpr int S_CNT = 12;
constexpr int NL    = 4;
constexpr int NV    = 258;
constexpr int TT    = 16;
constexpr int NSEQ  = 512;
constexpr int EOS_I = 257;
constexpr int NTH   = 768;
constexpr int SPB   = 4;                 // sequences per block
constexpr float RSCALE = 0.14433756729740646f;  // 1/sqrt(48)

typedef _Float16 h2 __attribute__((ext_vector_type(2)));
typedef _Float16 h8 __attribute__((ext_vector_type(8)));

union W16 { h8 v8; h2 h[4]; _Float16 e[8]; };

template<int N> struct IC { static constexpr int value = N; };

__device__ __forceinline__ float fdot2(h2 a, h2 b, float c) {
#if __has_builtin(__builtin_amdgcn_fdot2)
  return __builtin_amdgcn_fdot2(a, b, c, false);
#else
  return c + (float)a.x * (float)b.x + (float)a.y * (float)b.y;
#endif
}

// ---- repack prepass: dst[(j8*stride3+off3)*C + c] = {g[8j8+r]*src[8*j8+r][c]} ----
__global__ __launch_bounds__(256)
void pack8_kernel(const float* __restrict__ src, const float* __restrict__ g,
                  h8* __restrict__ dst, int C, int stride3, int off3) {
  int c  = blockIdx.x * 256 + threadIdx.x;
  int j8 = blockIdx.y;
  if (c < C) {
    h8 v;
    #pragma unroll
    for (int r = 0; r < 8; r++) {
      int row = 8 * j8 + r;
      float s = g ? g[row] : 1.0f;
      v[r] = (_Float16)(src[(size_t)row * C + c] * s);
    }
    dst[((size_t)j8 * stride3 + off3) * C + c] = v;
  }
}

__global__ __launch_bounds__(NTH)
void decoder_kernel(const float* __restrict__ x,
                    const h8* __restrict__ Wproj8,   // [128][1536]
                    const h8* __restrict__ Wqkv8,    // [(l*48+j8)*3+m][384], gamma-folded
                    const h8* __restrict__ Wo8,      // [l*48][384]
                    const h8* __restrict__ W18,      // [l*48][1536], gamma-folded
                    const h8* __restrict__ W28,      // [l*192][384]
                    const h8* __restrict__ Wlm8,     // [48][258]
                    float* __restrict__ out,
                    _Float16* __restrict__ kbuf,
                    _Float16* __restrict__ vbuf)
{
  __shared__ float xs[SPB][4][BH];                     // residual stream (f32) 24.6K
  __shared__ __align__(16) _Float16 xh[SPB][4][BH];    // residual f16 12.3K
  __shared__ __align__(16) _Float16 qh[SPB][4][BH];    // q (pre-scaled) 12.3K
  __shared__ __align__(16) _Float16 oh[SPB][4][BH];    // attn out 12.3K
  __shared__ __align__(16) _Float16 k_cur[SPB][4][BH]; // this step's K rows 12.3K
  __shared__ __align__(16) _Float16 v_cur[SPB][4][BH]; // this step's V rows 12.3K
  __shared__ float sc[SPB][NH][4][TT];                 // 8.2K
  // Partial-exchange slots indexed by ls*NT+tok (ls = block-local seq of the
  // published value) -> writer/reader sets disjoint across kg halves.
  __shared__ __align__(16) union Scr {                 // 61.4K
    float qkvp[3][8][BH];                              // QKV partials 36.9K
    float wop[8][BH];                                  // Wo partials 12.3K
    struct { __align__(16) _Float16 f1h[SPB][4][4*BH]; // gelu out f16 (49.2K)
             float w2p[8][BH]; } ffn;                  // W2 partials (12.3K)
    __align__(16) _Float16 xin[SPB][H_IN];             // staged input x (8K)
  } scr;
  __shared__ float redsq[SPB][4][6];                   // x^2 wave-sums per (seq,tok)
  __shared__ float redv[SPB * 6];
  __shared__ int   redi[SPB * 6];
  __shared__ int   fin[SPB];

  const int tid = threadIdx.x;
  const int kg  = tid / BH;        // split-K group (0/1); also seq-half index
  const int col = tid - kg * BH;   // 0..383
  const int wid = tid >> 6;        // wave id 0..11
  const int w6  = wid % 6;
  const int seq0 = blockIdx.x * SPB;

  if (tid < SPB) fin[tid] = 0;

  // ---- stage x as f16 ----
  for (int s = 0; s < SPB; s++) {
    const size_t base = (size_t)(seq0 + s) * H_IN;
    for (int j = tid; j < H_IN; j += NTH) scr.xin[s][j] = (_Float16)x[base + j];
  }
  __syncthreads();
  // ---- x0 = (x_row @ Wproj).reshape(P, BH); epilogue fuses f16 stage + x^2 sums ----
  {
    float acc[SPB][2] = {};
    for (int j8 = 0; j8 < H_IN / 8; j8 += 4) {
      W16 w0[4], w1[4];
      #pragma unroll
      for (int u = 0; u < 4; u++) {
        w0[u].v8 = Wproj8[(size_t)(j8 + u) * (PP * BH) + tid];
        w1[u].v8 = Wproj8[(size_t)(j8 + u) * (PP * BH) + tid + NTH];
      }
      #pragma unroll
      for (int u = 0; u < 4; u++)
        #pragma unroll
        for (int s = 0; s < SPB; s++) {
          W16 hv; hv.v8 = *(const h8*)&scr.xin[s][(j8 + u) * 8];
          #pragma unroll
          for (int r = 0; r < 4; r++) {
            acc[s][0] = fdot2(hv.h[r], w0[u].h[r], acc[s][0]);
            acc[s][1] = fdot2(hv.h[r], w1[u].h[r], acc[s][1]);
          }
        }
    }
    const int m0 = tid / BH, cc = tid - m0 * BH;     // tok pair (m0, m0+2)
    #pragma unroll
    for (int s = 0; s < SPB; s++) {
      xs[s][m0][cc]     = acc[s][0];  xh[s][m0][cc]     = (_Float16)acc[s][0];
      xs[s][m0 + 2][cc] = acc[s][1];  xh[s][m0 + 2][cc] = (_Float16)acc[s][1];
      float r0 = acc[s][0] * acc[s][0], r1 = acc[s][1] * acc[s][1];
      #pragma unroll
      for (int off = 32; off; off >>= 1) {
        r0 += __shfl_down(r0, off, 64); r1 += __shfl_down(r1, off, 64);
      }
      if ((tid & 63) == 0) { redsq[s][m0][w6] = r0; redsq[s][m0 + 2][w6] = r1; }
    }
  }
  __syncthreads();

  // NT = tokens this pass, SB = seqs this pass (local 0..SB map to base+s).
  auto layers = [&](auto ntc, auto sbc, int base, int pos, bool causal) {
    constexpr int NT = decltype(ntc)::value;
    constexpr int SB = decltype(sbc)::value;
    constexpr int HB = SB / 2;     // seqs finalized per kg-half
    const int nk = pos + NT;
    for (int l = 0; l < NL; l++) {
      // ==== q,k,v = sca * (x @ gW) (split-K; split-s epilogue over HB seqs) ====
      {
        const size_t wb3 = ((size_t)(l * 48 + kg * 24) * 3) * BH + col;
        float aq[SB][NT] = {}, ak[SB][NT] = {}, av[SB][NT] = {};
        for (int j8 = 0; j8 < 24; j8 += 4) {
          W16 wq[4], wk[4], wv[4];
          #pragma unroll
          for (int u = 0; u < 4; u++) {
            const size_t rb = wb3 + (size_t)(j8 + u) * 3 * BH;
            wq[u].v8 = Wqkv8[rb];
            wk[u].v8 = Wqkv8[rb + BH];
            wv[u].v8 = Wqkv8[rb + 2 * BH];
          }
          #pragma unroll
          for (int u = 0; u < 4; u++)
            #pragma unroll
            for (int s = 0; s < SB; s++)
              #pragma unroll
              for (int tok = 0; tok < NT; tok++) {
                W16 hv; hv.v8 = *(const h8*)&xh[base + s][tok][(kg * 24 + j8 + u) * 8];
                #pragma unroll
                for (int r = 0; r < 4; r++) {
                  aq[s][tok] = fdot2(hv.h[r], wq[u].h[r], aq[s][tok]);
                  ak[s][tok] = fdot2(hv.h[r], wk[u].h[r], ak[s][tok]);
                  av[s][tok] = fdot2(hv.h[r], wv[u].h[r], av[s][tok]);
                }
              }
        }
        {
          // publish partials for the seqs the OTHER half finalizes, at slot ls*NT+tok
          #pragma unroll
          for (int s2 = 0; s2 < HB; s2++) {
            const int ls = (kg ^ 1) * HB + s2;
            #pragma unroll
            for (int tok = 0; tok < NT; tok++) {
              scr.qkvp[0][ls * NT + tok][col] = aq[ls][tok];
              scr.qkvp[1][ls * NT + tok][col] = ak[ls][tok];
              scr.qkvp[2][ls * NT + tok][col] = av[ls][tok];
            }
          }
        }
        __syncthreads();
        {
          #pragma unroll
          for (int s2 = 0; s2 < HB; s2++) {
            const int ls = kg * HB + s2;
            const int gs = base + ls;
            const size_t cb = (((size_t)(seq0 + gs) * NL + l) * TT + pos) * BH + col;
            #pragma unroll
            for (int tok = 0; tok < NT; tok++) {
              float ss = redsq[gs][tok][0] + redsq[gs][tok][1] + redsq[gs][tok][2] +
                         redsq[gs][tok][3] + redsq[gs][tok][4] + redsq[gs][tok][5];
              float sca = rsqrtf(ss * (1.0f / BH) + 1e-5f);
              float kv_ = (ak[ls][tok] + scr.qkvp[1][ls * NT + tok][col]) * sca;
              float vv_ = (av[ls][tok] + scr.qkvp[2][ls * NT + tok][col]) * sca;
              qh[gs][tok][col] = (_Float16)((aq[ls][tok] + scr.qkvp[0][ls * NT + tok][col]) * sca * RSCALE);
              k_cur[gs][tok][col] = (_Float16)kv_;
              v_cur[gs][tok][col] = (_Float16)vv_;
              kbuf[cb + (size_t)tok * BH] = (_Float16)kv_;
              vbuf[cb + (size_t)tok * BH] = (_Float16)vv_;
            }
          }
        }
        __syncthreads();
      }
      // ==== scores + softmax (RSCALE pre-folded into q) ====
      if constexpr (NT == 1) {
        // fused: SPB*NH*TT = 512 threads, one (s,h,j) per lane; 16-lane shfl
        if (tid < SPB * NH * TT) {
          const int s = tid >> 7, r = tid & 127, h = r >> 4, j = r & 15;
          float d = -1e30f;
          if (j < nk) {
            const h8* kp8 = (j == pos)
                ? (const h8*)&k_cur[s][0][h * HD]
                : (const h8*)(kbuf + (((size_t)(seq0 + s) * NL + l) * TT + j) * BH + h * HD);
            d = 0.f;
            #pragma unroll
            for (int c6 = 0; c6 < 6; c6++) {
              W16 kk, qq;
              kk.v8 = kp8[c6];
              qq.v8 = *(const h8*)&qh[s][0][h * HD + c6 * 8];
              #pragma unroll
              for (int rr = 0; rr < 4; rr++) d = fdot2(qq.h[rr], kk.h[rr], d);
            }
          }
          float m = d;
          #pragma unroll
          for (int off = 8; off; off >>= 1) m = fmaxf(m, __shfl_xor(m, off, 16));
          float e = expf(d - m);
          float den = e;
          #pragma unroll
          for (int off = 8; off; off >>= 1) den += __shfl_xor(den, off, 16);
          sc[s][h][0][j] = e * (1.0f / den);
        }
        __syncthreads();
      } else {
        // step 0: all nk rows are current-step -> K from LDS only
        {
          const int nu = SB * NH * NT * nk;   // 256
          if (tid < nu) {
            int s = tid / (NH * NT * nk), r = tid % (NH * NT * nk);
            int h = r / (NT * nk); int r2 = r % (NT * nk);
            int qi = r2 / nk, j = r2 % nk;
            const int gs = base + s;
            float d;
            if (causal && j > pos + qi) d = -1e30f;
            else {
              d = 0.f;
              #pragma unroll
              for (int c6 = 0; c6 < 6; c6++) {
                W16 kk, qq;
                kk.v8 = *(const h8*)&k_cur[gs][j][h * HD + c6 * 8];
                qq.v8 = *(const h8*)&qh[gs][qi][h * HD + c6 * 8];
                #pragma unroll
                for (int rr = 0; rr < 4; rr++) d = fdot2(qq.h[rr], kk.h[rr], d);
              }
            }
            sc[gs][h][qi][j] = d;
          }
        }
        __syncthreads();
        {
          const int nr = SB * NH * NT;
          if (tid < nr) {
            int s = tid / (NH * NT), r = tid % (NH * NT);
            int h = r / NT, qi = r % NT;
            const int gs = base + s;
            float m = -3.0e38f;
            for (int j = 0; j < nk; j++) m = fmaxf(m, sc[gs][h][qi][j]);
            float den = 0.f;
            for (int j = 0; j < nk; j++) {
              float e = expf(sc[gs][h][qi][j] - m);
              sc[gs][h][qi][j] = e; den += e;
            }
            float inv = 1.0f / den;
            for (int j = 0; j < nk; j++) sc[gs][h][qi][j] *= inv;
          }
        }
        __syncthreads();
      }
      // ==== o = p @ V (kg half handles its HB seqs) ====
      {
        const int h = col / HD;
        #pragma unroll
        for (int s2 = 0; s2 < HB; s2++) {
          const int gs = base + kg * HB + s2;
          const size_t vb = (((size_t)(seq0 + gs) * NL + l) * TT) * BH + col;
          #pragma unroll
          for (int tok = 0; tok < NT; tok++) {
            float acc = 0.f;
            if constexpr (NT == 1) {
              int j = 0;
              for (; j + 4 <= pos; j += 4) {
                float v0 = (float)vbuf[vb + (size_t)(j + 0) * BH];
                float v1 = (float)vbuf[vb + (size_t)(j + 1) * BH];
                float v2 = (float)vbuf[vb + (size_t)(j + 2) * BH];
                float v3 = (float)vbuf[vb + (size_t)(j + 3) * BH];
                acc += sc[gs][h][0][j] * v0 + sc[gs][h][0][j + 1] * v1 +
                       sc[gs][h][0][j + 2] * v2 + sc[gs][h][0][j + 3] * v3;
              }
              for (; j < pos; j++)
                acc += sc[gs][h][0][j] * (float)vbuf[vb + (size_t)j * BH];
              acc += sc[gs][h][0][pos] * (float)v_cur[gs][0][col];
            } else {
              #pragma unroll
              for (int j = 0; j < 4; j++)
                acc += sc[gs][h][tok][j] * (float)v_cur[gs][j][col];
            }
            oh[gs][tok][col] = (_Float16)acc;
          }
        }
      }
      __syncthreads();
      // ==== x += o @ Wo (split-K; split-s epilogue fuses xh + x^2) ====
      {
        const size_t wb = ((size_t)l * 48 + kg * 24) * BH + col;
        float ao[SB][NT] = {};
        for (int j8 = 0; j8 < 24; j8 += 8) {
          W16 w[8];
          #pragma unroll
          for (int u = 0; u < 8; u++) w[u].v8 = Wo8[wb + (size_t)(j8 + u) * BH];
          #pragma unroll
          for (int u = 0; u < 8; u++)
            #pragma unroll
            for (int s = 0; s < SB; s++)
              #pragma unroll
              for (int tok = 0; tok < NT; tok++) {
                W16 hv; hv.v8 = *(const h8*)&oh[base + s][tok][(kg * 24 + j8 + u) * 8];
                #pragma unroll
                for (int r = 0; r < 4; r++)
                  ao[s][tok] = fdot2(hv.h[r], w[u].h[r], ao[s][tok]);
              }
        }
        {
          #pragma unroll
          for (int s2 = 0; s2 < HB; s2++) {
            const int ls = (kg ^ 1) * HB + s2;
            #pragma unroll
            for (int tok = 0; tok < NT; tok++)
              scr.wop[ls * NT + tok][col] = ao[ls][tok];
          }
        }
        __syncthreads();
        {
          #pragma unroll
          for (int s2 = 0; s2 < HB; s2++) {
            const int ls = kg * HB + s2;
            const int gs = base + ls;
            #pragma unroll
            for (int tok = 0; tok < NT; tok++) {
              float xn = xs[gs][tok][col] + ao[ls][tok] + scr.wop[ls * NT + tok][col];
              xs[gs][tok][col] = xn; xh[gs][tok][col] = (_Float16)xn;
              float r = xn * xn;
              #pragma unroll
              for (int off = 32; off; off >>= 1) r += __shfl_down(r, off, 64);
              if ((tid & 63) == 0) redsq[gs][tok][w6] = r;
            }
          }
        }
        __syncthreads();
      }
      // ==== x += gelu(sca2 * (x @ gW1)) @ W2 (gamma folded; sca2 at gelu) ====
      {
        float a1[SB][NT][2] = {};
        for (int j8 = 0; j8 < 48; j8 += 4) {
          W16 w0[4], w1[4];
          #pragma unroll
          for (int u = 0; u < 4; u++) {
            w0[u].v8 = W18[((size_t)(l * 48 + j8 + u)) * (4 * BH) + tid];
            w1[u].v8 = W18[((size_t)(l * 48 + j8 + u)) * (4 * BH) + tid + NTH];
          }
          #pragma unroll
          for (int u = 0; u < 4; u++)
            #pragma unroll
            for (int s = 0; s < SB; s++)
              #pragma unroll
              for (int t = 0; t < NT; t++) {
                W16 hv; hv.v8 = *(const h8*)&xh[base + s][t][(j8 + u) * 8];
                #pragma unroll
                for (int r = 0; r < 4; r++) {
                  a1[s][t][0] = fdot2(hv.h[r], w0[u].h[r], a1[s][t][0]);
                  a1[s][t][1] = fdot2(hv.h[r], w1[u].h[r], a1[s][t][1]);
                }
              }
        }
        #pragma unroll
        for (int s = 0; s < SB; s++)
          #pragma unroll
          for (int t = 0; t < NT; t++) {
            const int gs = base + s;
            float ss = redsq[gs][t][0] + redsq[gs][t][1] + redsq[gs][t][2] +
                       redsq[gs][t][3] + redsq[gs][t][4] + redsq[gs][t][5];
            float sca = rsqrtf(ss * (1.0f / BH) + 1e-5f);
            float z0 = a1[s][t][0] * sca, z1 = a1[s][t][1] * sca;
            scr.ffn.f1h[gs][t][tid]       = (_Float16)(0.5f * z0 * (1.0f + erff(z0 * 0.7071067811865476f)));
            scr.ffn.f1h[gs][t][tid + NTH] = (_Float16)(0.5f * z1 * (1.0f + erff(z1 * 0.7071067811865476f)));
          }
        __syncthreads();
        // W2: split-K; split-s epilogue fuses xh stage + x^2 sums.
        // On the LAST layer also fuses phase-A (argmax partials + next-token copy).
        {
          float a2[SB][NT] = {};
          for (int j8 = 0; j8 < 96; j8 += 8) {
            W16 w[8];
            #pragma unroll
            for (int u = 0; u < 8; u++)
              w[u].v8 = W28[((size_t)(l * 192 + kg * 96 + j8 + u)) * BH + col];
            #pragma unroll
            for (int u = 0; u < 8; u++)
              #pragma unroll
              for (int s = 0; s < SB; s++)
                #pragma unroll
                for (int t = 0; t < NT; t++) {
                  W16 fv; fv.v8 = *(const h8*)&scr.ffn.f1h[base + s][t][(kg * 96 + j8 + u) * 8];
                  #pragma unroll
                  for (int r = 0; r < 4; r++)
                    a2[s][t] = fdot2(fv.h[r], w[u].h[r], a2[s][t]);
                }
          }
          {
            #pragma unroll
            for (int s2 = 0; s2 < HB; s2++) {
              const int ls = (kg ^ 1) * HB + s2;
              #pragma unroll
              for (int t = 0; t < NT; t++)
                scr.ffn.w2p[ls * NT + t][col] = a2[ls][t];
            }
          }
          __syncthreads();
          {
            #pragma unroll
            for (int s2 = 0; s2 < HB; s2++) {
              const int ls = kg * HB + s2;
              const int gs = base + ls;
              #pragma unroll
              for (int t = 0; t < NT; t++) {
                float xn = xs[gs][t][col] + a2[ls][t] + scr.ffn.w2p[ls * NT + t][col];
                xs[gs][t][col] = xn; xh[gs][t][col] = (_Float16)xn;
                float r = xn * xn;
                #pragma unroll
                for (int off = 32; off; off >>= 1) r += __shfl_down(r, off, 64);
                if ((tid & 63) == 0) redsq[gs][t][w6] = r;
                if (t == NT - 1 && l == NL - 1) {
                  // fused phase A: argmax partials on xn + next-token copy
                  float v = xn; int idx = col;
                  #pragma unroll
                  for (int off = 32; off; off >>= 1) {
                    float v2 = __shfl_down(v, off, 64); int i2 = __shfl_down(idx, off, 64);
                    if (v2 > v || (v2 == v && i2 < idx)) { v = v2; idx = i2; }
                  }
                  if ((tid & 63) == 0) { redv[gs * 6 + w6] = v; redi[gs * 6 + w6] = idx; }
                  float nxt = fin[gs] ? 0.0f : xn;
                  xs[gs][0][col] = nxt; xh[gs][0][col] = (_Float16)nxt;
                  float rn = nxt * nxt;
                  #pragma unroll
                  for (int off = 32; off; off >>= 1) rn += __shfl_down(rn, off, 64);
                  if ((tid & 63) == 0) redsq[gs][0][w6] = rn;
                }
              }
            }
          }
          __syncthreads();
        }
      }
    }
  };

  for (int i = 0; i < S_CNT; i++) {
    if (i == 0) {
      layers(IC<4>{}, IC<2>{}, 0, 0, true);   // seqs 0,1 (register-safe NT=4 pass)
      layers(IC<4>{}, IC<2>{}, 2, 0, true);   // seqs 2,3
    } else {
      layers(IC<1>{}, IC<4>{}, 0, PP + i - 1, false);  // all 4 seqs, one weight pass
    }

    // ---- phase B: argmax finalize (+fin update) + fin-free logits (2 seqs/half) ----
    {
      if (col == 0) {
        #pragma unroll
        for (int s2 = 0; s2 < 2; s2++) {
          const int gs = kg * 2 + s2;
          const int b = gs * 6;
          float bv = redv[b]; int bi = redi[b];
          for (int w = 1; w < 6; w++)
            if (redv[b + w] > bv || (redv[b + w] == bv && redi[b + w] < bi)) {
              bv = redv[b + w]; bi = redi[b + w];
            }
          if (bi == EOS_I) fin[gs] = 1;
        }
      }
      if (col < NV) {
        float acc[2] = {};
        for (int j8 = 0; j8 < 48; j8 += 8) {
          W16 w[8];
          #pragma unroll
          for (int u = 0; u < 8; u++) w[u].v8 = Wlm8[(size_t)(j8 + u) * NV + col];
          #pragma unroll
          for (int u = 0; u < 8; u++)
            #pragma unroll
            for (int s2 = 0; s2 < 2; s2++) {
              W16 gv; gv.v8 = *(const h8*)&xh[kg * 2 + s2][0][(j8 + u) * 8];
              #pragma unroll
              for (int r = 0; r < 4; r++) acc[s2] = fdot2(gv.h[r], w[u].h[r], acc[s2]);
            }
        }
        #pragma unroll
        for (int s2 = 0; s2 < 2; s2++)
          out[((size_t)(seq0 + kg * 2 + s2) * S_CNT + i) * NV + col] = acc[s2];
      }
      __syncthreads();
    }
  }
}

extern "C" void kernel_launch(void* const* d_in, const int* in_sizes, int n_in,
                              void* d_out, int out_size, void* d_ws, size_t ws_size,
                              hipStream_t stream) {
  const float* x     = (const float*)d_in[0];
  // d_in[1] = target (unused)
  const float* Wproj = (const float*)d_in[2];
  const float* an    = (const float*)d_in[3];
  const float* Wq    = (const float*)d_in[4];
  const float* Wk    = (const float*)d_in[5];
  const float* Wv    = (const float*)d_in[6];
  const float* Wo    = (const float*)d_in[7];
  const float* fn    = (const float*)d_in[8];
  const float* W1    = (const float*)d_in[9];
  const float* W2    = (const float*)d_in[10];
  const float* Wlm   = (const float*)d_in[11];
  float* out = (float*)d_out;
  (void)ws_size; (void)in_sizes; (void)n_in; (void)out_size;

  // ---- carve d_ws: h8-packed weights (gamma folded into Wq/Wk/Wv/W1), then f16 KV ----
  h8* w = (h8*)d_ws;
  const int n_proj = (H_IN / 8) * (PP * BH);
  const int n_qkv  = NL * (BH / 8) * BH * 3;   // fused interleaved QKV
  const int n_qkvo = NL * (BH / 8) * BH;
  const int n_w1   = NL * (BH / 8) * (4 * BH);
  const int n_w2   = NL * (4 * BH / 8) * BH;
  const int n_lm   = (BH / 8) * NV;
  h8* Wproj_p = w;  w += n_proj;
  h8* Wqkv_p  = w;  w += n_qkv;
  h8* Wo_p    = w;  w += n_qkvo;
  h8* W1_p    = w;  w += n_w1;
  h8* W2_p    = w;  w += n_w2;
  h8* Wlm_p   = w;  w += n_lm;
  const size_t kv_elems = (size_t)NSEQ * NL * TT * BH;
  _Float16* kbuf = (_Float16*)w;
  _Float16* vbuf = kbuf + kv_elems;

  auto pack = [&](const float* src, const float* g, h8* dst, int R, int C,
                  int stride3, int off3) {
    dim3 grid((C + 255) / 256, R / 8);
    pack8_kernel<<<grid, 256, 0, stream>>>(src, g, dst, C, stride3, off3);
  };
  pack(Wproj, nullptr, Wproj_p, H_IN,        PP * BH, 1, 0);
  pack(Wq,    an,      Wqkv_p,  NL * BH,     BH,      3, 0);
  pack(Wk,    an,      Wqkv_p,  NL * BH,     BH,      3, 1);
  pack(Wv,    an,      Wqkv_p,  NL * BH,     BH,      3, 2);
  pack(Wo,    nullptr, Wo_p,    NL * BH,     BH,      1, 0);
  pack(W1,    fn,      W1_p,    NL * BH,     4 * BH,  1, 0);
  pack(W2,    nullptr, W2_p,    NL * 4 * BH, BH,      1, 0);
  pack(Wlm,   nullptr, Wlm_p,   BH,          NV,      1, 0);

  decoder_kernel<<<NSEQ / SPB, NTH, 0, stream>>>(
      x, Wproj_p, Wqkv_p, Wo_p, W1_p, W2_p, Wlm_p, out, kbuf, vbuf);
}

// Round 13
// 2219.046 us; speedup vs baseline: 1.6101x; 1.6101x over previous
//
#include <hip/hip_runtime.h>
#include <hip/hip_bf16.h>

// ByteLevelDecoder: B=2,S=256,H=1024, BH=384,NH=8,HD=48, P=4,S_C=12,L=4,V=258,T=16
// Persistent kernel, 1 block = 2 sequences, 768 threads = 12 waves/CU.
// Round 21: revert SPB=4 (half the CUs idle at grid 128 -> 3573us). Back to
// the 2333-2340us SPB=2 body + PHASE-STAGGERED weight streams: each block
// rotates its GEMV chunk order by rot=(blockIdx>>3) so same-XCD blocks stop
// requesting the SAME L2 lines in lockstep (tests same-line serialization vs
// true fabric ceiling; 2.33 TB/s/XCD measured vs 4.3 ceiling). Same bytes,
// same work; only instantaneous address correlation changes. Accumulation
// order changes -> absmax wiggles (f16-level, << 0.153 threshold).

constexpr int H_IN  = 1024;
constexpr int BH    = 384;
constexpr int NH    = 8;
constexpr int HD    = 48;
constexpr int PP    = 4;
constexpr int S_CNT = 12;
constexpr int NL    = 4;
constexpr int NV    = 258;
constexpr int TT    = 16;
constexpr int NSEQ  = 512;
constexpr int EOS_I = 257;
constexpr int NTH   = 768;
constexpr float RSCALE = 0.14433756729740646f;  // 1/sqrt(48)

typedef _Float16 h2 __attribute__((ext_vector_type(2)));
typedef _Float16 h8 __attribute__((ext_vector_type(8)));

union W16 { h8 v8; h2 h[4]; _Float16 e[8]; };

template<int N> struct IC { static constexpr int value = N; };

__device__ __forceinline__ float fdot2(h2 a, h2 b, float c) {
#if __has_builtin(__builtin_amdgcn_fdot2)
  return __builtin_amdgcn_fdot2(a, b, c, false);
#else
  return c + (float)a.x * (float)b.x + (float)a.y * (float)b.y;
#endif
}

// ---- repack prepass: dst[(j8*stride3+off3)*C + c] = {g[8j8+r]*src[8*j8+r][c]} ----
__global__ __launch_bounds__(256)
void pack8_kernel(const float* __restrict__ src, const float* __restrict__ g,
                  h8* __restrict__ dst, int C, int stride3, int off3) {
  int c  = blockIdx.x * 256 + threadIdx.x;
  int j8 = blockIdx.y;
  if (c < C) {
    h8 v;
    #pragma unroll
    for (int r = 0; r < 8; r++) {
      int row = 8 * j8 + r;
      float s = g ? g[row] : 1.0f;
      v[r] = (_Float16)(src[(size_t)row * C + c] * s);
    }
    dst[((size_t)j8 * stride3 + off3) * C + c] = v;
  }
}

__global__ __launch_bounds__(NTH)
void decoder_kernel(const float* __restrict__ x,
                    const h8* __restrict__ Wproj8,   // [128][1536]
                    const h8* __restrict__ Wqkv8,    // [(l*48+j8)*3+m][384], gamma-folded
                    const h8* __restrict__ Wo8,      // [l*48][384]
                    const h8* __restrict__ W18,      // [l*48][1536], gamma-folded
                    const h8* __restrict__ W28,      // [l*192][384]
                    const h8* __restrict__ Wlm8,     // [48][258]
                    float* __restrict__ out,
                    _Float16* __restrict__ kbuf,
                    _Float16* __restrict__ vbuf)
{
  __shared__ float xs[2][4][BH];                     // residual stream (f32)
  __shared__ __align__(16) _Float16 xh[2][4][BH];    // residual as f16 (GEMM input)
  __shared__ __align__(16) _Float16 qh[2][4][BH];    // q (f16, pre-scaled)
  __shared__ __align__(16) _Float16 oh[2][4][BH];    // attention out (f16)
  __shared__ __align__(16) _Float16 k_cur[2][4][BH]; // this step's K rows (6KB)
  __shared__ __align__(16) _Float16 v_cur[2][4][BH]; // this step's V rows (6KB)
  __shared__ float sc[2][NH][4][TT];
  __shared__ __align__(16) union Scr {
    float qkvp[3][2][4][BH];                         // QKV split-K partials (36KB)
    float wop[2][4][BH];                             // Wo partials (12KB)
    struct { __align__(16) _Float16 f1h[2][4][4*BH]; // gelu out f16 (24KB)
             float w2p[2][4][BH]; } ffn;             // W2 partials (12KB)
    __align__(16) _Float16 xin[2][H_IN];             // staged input x (4KB)
  } scr;
  __shared__ float redsq[2][4][6];                   // x^2 wave-sums per (s,tok)
  __shared__ float redv[12];
  __shared__ int   redi[12];
  __shared__ int   fin[2];

  const int tid = threadIdx.x;
  const int kg  = tid / BH;        // split-K group (0/1); also seq index
  const int col = tid - kg * BH;   // 0..383
  const int sq  = kg;
  const int wid = tid >> 6;        // wave id 0..11
  const int w6  = wid % 6;
  const int seq0 = blockIdx.x * 2;
  const int rot  = (int)(blockIdx.x >> 3);  // same-XCD blocks -> consecutive rot

  if (tid < 2) fin[tid] = 0;

  // ---- stage x as f16 ----
  for (int s = 0; s < 2; s++) {
    const size_t base = (size_t)(seq0 + s) * H_IN;
    for (int j = tid; j < H_IN; j += NTH) scr.xin[s][j] = (_Float16)x[base + j];
  }
  __syncthreads();
  // ---- x0 = (x_row @ Wproj).reshape(P, BH); epilogue fuses f16 stage + x^2 sums ----
  {
    float acc[2][2] = {};
    for (int j8 = 0; j8 < H_IN / 8; j8 += 4) {
      W16 w0[4], w1[4];
      #pragma unroll
      for (int u = 0; u < 4; u++) {
        w0[u].v8 = Wproj8[(size_t)(j8 + u) * (PP * BH) + tid];
        w1[u].v8 = Wproj8[(size_t)(j8 + u) * (PP * BH) + tid + NTH];
      }
      #pragma unroll
      for (int u = 0; u < 4; u++)
        #pragma unroll
        for (int s = 0; s < 2; s++) {
          W16 hv; hv.v8 = *(const h8*)&scr.xin[s][(j8 + u) * 8];
          #pragma unroll
          for (int r = 0; r < 4; r++) {
            acc[s][0] = fdot2(hv.h[r], w0[u].h[r], acc[s][0]);
            acc[s][1] = fdot2(hv.h[r], w1[u].h[r], acc[s][1]);
          }
        }
    }
    const int m0 = tid / BH, cc = tid - m0 * BH;     // tok pair (m0, m0+2)
    #pragma unroll
    for (int s = 0; s < 2; s++) {
      xs[s][m0][cc]     = acc[s][0];  xh[s][m0][cc]     = (_Float16)acc[s][0];
      xs[s][m0 + 2][cc] = acc[s][1];  xh[s][m0 + 2][cc] = (_Float16)acc[s][1];
      float r0 = acc[s][0] * acc[s][0], r1 = acc[s][1] * acc[s][1];
      #pragma unroll
      for (int off = 32; off; off >>= 1) {
        r0 += __shfl_down(r0, off, 64); r1 += __shfl_down(r1, off, 64);
      }
      if ((tid & 63) == 0) { redsq[s][m0][w6] = r0; redsq[s][m0 + 2][w6] = r1; }
    }
  }
  __syncthreads();

  auto layers = [&](auto ntc, int pos, bool causal) {
    constexpr int NT = decltype(ntc)::value;
    const int nk = pos + NT;
    for (int l = 0; l < NL; l++) {
      // ==== q,k,v = sca * (x @ gW) (split-K, staggered chunk order) ====
      {
        const size_t wb3 = ((size_t)(l * 48 + kg * 24) * 3) * BH + col;
        float aq[2][NT] = {}, ak[2][NT] = {}, av[2][NT] = {};
        for (int c = 0; c < 6; c++) {
          const int j8 = ((c + rot) % 6) * 4;
          W16 wq[4], wk[4], wv[4];
          #pragma unroll
          for (int u = 0; u < 4; u++) {
            const size_t rb = wb3 + (size_t)(j8 + u) * 3 * BH;
            wq[u].v8 = Wqkv8[rb];
            wk[u].v8 = Wqkv8[rb + BH];
            wv[u].v8 = Wqkv8[rb + 2 * BH];
          }
          #pragma unroll
          for (int u = 0; u < 4; u++)
            #pragma unroll
            for (int s = 0; s < 2; s++)
              #pragma unroll
              for (int tok = 0; tok < NT; tok++) {
                W16 hv; hv.v8 = *(const h8*)&xh[s][tok][(kg * 24 + j8 + u) * 8];
                #pragma unroll
                for (int r = 0; r < 4; r++) {
                  aq[s][tok] = fdot2(hv.h[r], wq[u].h[r], aq[s][tok]);
                  ak[s][tok] = fdot2(hv.h[r], wk[u].h[r], ak[s][tok]);
                  av[s][tok] = fdot2(hv.h[r], wv[u].h[r], av[s][tok]);
                }
              }
        }
        {
          const int so = kg ^ 1;  // publish partials for the OTHER seq
          #pragma unroll
          for (int tok = 0; tok < NT; tok++) {
            scr.qkvp[0][so][tok][col] = aq[so][tok];
            scr.qkvp[1][so][tok][col] = ak[so][tok];
            scr.qkvp[2][so][tok][col] = av[so][tok];
          }
        }
        __syncthreads();
        {
          const int s = kg;       // finalize own seq
          const size_t cb = (((size_t)(seq0 + s) * NL + l) * TT + pos) * BH + col;
          #pragma unroll
          for (int tok = 0; tok < NT; tok++) {
            float ss = redsq[s][tok][0] + redsq[s][tok][1] + redsq[s][tok][2] +
                       redsq[s][tok][3] + redsq[s][tok][4] + redsq[s][tok][5];
            float sca = rsqrtf(ss * (1.0f / BH) + 1e-5f);
            float kv_ = (ak[s][tok] + scr.qkvp[1][s][tok][col]) * sca;
            float vv_ = (av[s][tok] + scr.qkvp[2][s][tok][col]) * sca;
            qh[s][tok][col] = (_Float16)((aq[s][tok] + scr.qkvp[0][s][tok][col]) * sca * RSCALE);
            k_cur[s][tok][col] = (_Float16)kv_;
            v_cur[s][tok][col] = (_Float16)vv_;
            kbuf[cb + (size_t)tok * BH] = (_Float16)kv_;
            vbuf[cb + (size_t)tok * BH] = (_Float16)vv_;
          }
        }
        __syncthreads();
      }
      // ==== scores + softmax (RSCALE pre-folded into q) ====
      if constexpr (NT == 1) {
        // fused: 256 threads, one (s,h,j) per lane; shfl reduce in 16-lane groups
        if (tid < 2 * NH * TT) {
          const int s = tid >> 7, r = tid & 127, h = r >> 4, j = r & 15;
          float d = -1e30f;
          if (j < nk) {
            const h8* kp8 = (j == pos)
                ? (const h8*)&k_cur[s][0][h * HD]
                : (const h8*)(kbuf + (((size_t)(seq0 + s) * NL + l) * TT + j) * BH + h * HD);
            d = 0.f;
            #pragma unroll
            for (int c6 = 0; c6 < 6; c6++) {
              W16 kk, qq;
              kk.v8 = kp8[c6];
              qq.v8 = *(const h8*)&qh[s][0][h * HD + c6 * 8];
              #pragma unroll
              for (int rr = 0; rr < 4; rr++) d = fdot2(qq.h[rr], kk.h[rr], d);
            }
          }
          float m = d;
          #pragma unroll
          for (int off = 8; off; off >>= 1) m = fmaxf(m, __shfl_xor(m, off, 16));
          float e = expf(d - m);
          float den = e;
          #pragma unroll
          for (int off = 8; off; off >>= 1) den += __shfl_xor(den, off, 16);
          sc[s][h][0][j] = e * (1.0f / den);
        }
        __syncthreads();
      } else {
        // step 0: all nk rows are current-step -> K from LDS only
        {
          const int nu = 2 * NH * NT * nk;   // 256
          if (tid < nu) {
            int s = tid / (NH * NT * nk), r = tid % (NH * NT * nk);
            int h = r / (NT * nk); int r2 = r % (NT * nk);
            int qi = r2 / nk, j = r2 % nk;
            float d;
            if (causal && j > pos + qi) d = -1e30f;
            else {
              d = 0.f;
              #pragma unroll
              for (int c6 = 0; c6 < 6; c6++) {
                W16 kk, qq;
                kk.v8 = *(const h8*)&k_cur[s][j][h * HD + c6 * 8];
                qq.v8 = *(const h8*)&qh[s][qi][h * HD + c6 * 8];
                #pragma unroll
                for (int rr = 0; rr < 4; rr++) d = fdot2(qq.h[rr], kk.h[rr], d);
              }
            }
            sc[s][h][qi][j] = d;
          }
        }
        __syncthreads();
        {
          const int nr = 2 * NH * NT;
          if (tid < nr) {
            int s = tid / (NH * NT), r = tid % (NH * NT);
            int h = r / NT, qi = r % NT;
            float m = -3.0e38f;
            for (int j = 0; j < nk; j++) m = fmaxf(m, sc[s][h][qi][j]);
            float den = 0.f;
            for (int j = 0; j < nk; j++) {
              float e = expf(sc[s][h][qi][j] - m);
              sc[s][h][qi][j] = e; den += e;
            }
            float inv = 1.0f / den;
            for (int j = 0; j < nk; j++) sc[s][h][qi][j] *= inv;
          }
        }
        __syncthreads();
      }
      // ==== o = p @ V (old rows from global, current rows from LDS) ====
      {
        const size_t vb = (((size_t)(seq0 + sq) * NL + l) * TT) * BH + col;
        const int h = col / HD;
        #pragma unroll
        for (int tok = 0; tok < NT; tok++) {
          float acc = 0.f;
          if constexpr (NT == 1) {
            int j = 0;
            for (; j + 4 <= pos; j += 4) {
              float v0 = (float)vbuf[vb + (size_t)(j + 0) * BH];
              float v1 = (float)vbuf[vb + (size_t)(j + 1) * BH];
              float v2 = (float)vbuf[vb + (size_t)(j + 2) * BH];
              float v3 = (float)vbuf[vb + (size_t)(j + 3) * BH];
              acc += sc[sq][h][0][j] * v0 + sc[sq][h][0][j + 1] * v1 +
                     sc[sq][h][0][j + 2] * v2 + sc[sq][h][0][j + 3] * v3;
            }
            for (; j < pos; j++)
              acc += sc[sq][h][0][j] * (float)vbuf[vb + (size_t)j * BH];
            acc += sc[sq][h][0][pos] * (float)v_cur[sq][0][col];
          } else {
            #pragma unroll
            for (int j = 0; j < 4; j++)
              acc += sc[sq][h][tok][j] * (float)v_cur[sq][j][col];
          }
          oh[sq][tok][col] = (_Float16)acc;
        }
      }
      __syncthreads();
      // ==== x += o @ Wo (split-K, staggered chunk order) ====
      {
        const size_t wb = ((size_t)l * 48 + kg * 24) * BH + col;
        float ao[2][NT] = {};
        for (int c = 0; c < 3; c++) {
          const int j8 = ((c + rot) % 3) * 8;
          W16 w[8];
          #pragma unroll
          for (int u = 0; u < 8; u++) w[u].v8 = Wo8[wb + (size_t)(j8 + u) * BH];
          #pragma unroll
          for (int u = 0; u < 8; u++)
            #pragma unroll
            for (int s = 0; s < 2; s++)
              #pragma unroll
              for (int tok = 0; tok < NT; tok++) {
                W16 hv; hv.v8 = *(const h8*)&oh[s][tok][(kg * 24 + j8 + u) * 8];
                #pragma unroll
                for (int r = 0; r < 4; r++)
                  ao[s][tok] = fdot2(hv.h[r], w[u].h[r], ao[s][tok]);
              }
        }
        {
          const int so = kg ^ 1;
          #pragma unroll
          for (int tok = 0; tok < NT; tok++) scr.wop[so][tok][col] = ao[so][tok];
        }
        __syncthreads();
        {
          const int s = kg;
          #pragma unroll
          for (int tok = 0; tok < NT; tok++) {
            float xn = xs[s][tok][col] + ao[s][tok] + scr.wop[s][tok][col];
            xs[s][tok][col] = xn; xh[s][tok][col] = (_Float16)xn;
            float r = xn * xn;
            #pragma unroll
            for (int off = 32; off; off >>= 1) r += __shfl_down(r, off, 64);
            if ((tid & 63) == 0) redsq[s][tok][w6] = r;
          }
        }
        __syncthreads();
      }
      // ==== x += gelu(sca2 * (x @ gW1)) @ W2 (staggered chunk order) ====
      {
        float a1[2][NT][2] = {};
        for (int c = 0; c < 12; c++) {
          const int j8 = ((c + rot) % 12) * 4;
          W16 w0[4], w1[4];
          #pragma unroll
          for (int u = 0; u < 4; u++) {
            w0[u].v8 = W18[((size_t)(l * 48 + j8 + u)) * (4 * BH) + tid];
            w1[u].v8 = W18[((size_t)(l * 48 + j8 + u)) * (4 * BH) + tid + NTH];
          }
          #pragma unroll
          for (int u = 0; u < 4; u++)
            #pragma unroll
            for (int s = 0; s < 2; s++)
              #pragma unroll
              for (int t = 0; t < NT; t++) {
                W16 hv; hv.v8 = *(const h8*)&xh[s][t][(j8 + u) * 8];
                #pragma unroll
                for (int r = 0; r < 4; r++) {
                  a1[s][t][0] = fdot2(hv.h[r], w0[u].h[r], a1[s][t][0]);
                  a1[s][t][1] = fdot2(hv.h[r], w1[u].h[r], a1[s][t][1]);
                }
              }
        }
        #pragma unroll
        for (int s = 0; s < 2; s++)
          #pragma unroll
          for (int t = 0; t < NT; t++) {
            float ss = redsq[s][t][0] + redsq[s][t][1] + redsq[s][t][2] +
                       redsq[s][t][3] + redsq[s][t][4] + redsq[s][t][5];
            float sca = rsqrtf(ss * (1.0f / BH) + 1e-5f);
            float z0 = a1[s][t][0] * sca, z1 = a1[s][t][1] * sca;
            scr.ffn.f1h[s][t][tid]       = (_Float16)(0.5f * z0 * (1.0f + erff(z0 * 0.7071067811865476f)));
            scr.ffn.f1h[s][t][tid + NTH] = (_Float16)(0.5f * z1 * (1.0f + erff(z1 * 0.7071067811865476f)));
          }
        __syncthreads();
        // W2: split-K, staggered chunk order; split-s epilogue fuses xh + x^2.
        // On the LAST layer also fuses phase-A (argmax partials + next-token copy).
        {
          float a2[2][NT] = {};
          for (int c = 0; c < 12; c++) {
            const int j8 = ((c + rot) % 12) * 8;
            W16 w[8];
            #pragma unroll
            for (int u = 0; u < 8; u++)
              w[u].v8 = W28[((size_t)(l * 192 + kg * 96 + j8 + u)) * BH + col];
            #pragma unroll
            for (int u = 0; u < 8; u++)
              #pragma unroll
              for (int s = 0; s < 2; s++)
                #pragma unroll
                for (int t = 0; t < NT; t++) {
                  W16 fv; fv.v8 = *(const h8*)&scr.ffn.f1h[s][t][(kg * 96 + j8 + u) * 8];
                  #pragma unroll
                  for (int r = 0; r < 4; r++)
                    a2[s][t] = fdot2(fv.h[r], w[u].h[r], a2[s][t]);
                }
          }
          {
            const int so = kg ^ 1;
            #pragma unroll
            for (int t = 0; t < NT; t++) scr.ffn.w2p[so][t][col] = a2[so][t];
          }
          __syncthreads();
          {
            const int s = kg;
            #pragma unroll
            for (int t = 0; t < NT; t++) {
              float xn = xs[s][t][col] + a2[s][t] + scr.ffn.w2p[s][t][col];
              xs[s][t][col] = xn; xh[s][t][col] = (_Float16)xn;
              float r = xn * xn;
              #pragma unroll
              for (int off = 32; off; off >>= 1) r += __shfl_down(r, off, 64);
              if ((tid & 63) == 0) redsq[s][t][w6] = r;
              if (t == NT - 1 && l == NL - 1) {
                // fused phase A: argmax partials on xn + next-token copy
                float v = xn; int idx = col;
                #pragma unroll
                for (int off = 32; off; off >>= 1) {
                  float v2 = __shfl_down(v, off, 64); int i2 = __shfl_down(idx, off, 64);
                  if (v2 > v || (v2 == v && i2 < idx)) { v = v2; idx = i2; }
                }
                if ((tid & 63) == 0) { redv[wid] = v; redi[wid] = idx; }
                float nxt = fin[s] ? 0.0f : xn;
                xs[s][0][col] = nxt; xh[s][0][col] = (_Float16)nxt;
                float rn = nxt * nxt;
                #pragma unroll
                for (int off = 32; off; off >>= 1) rn += __shfl_down(rn, off, 64);
                if ((tid & 63) == 0) redsq[s][0][w6] = rn;
              }
            }
          }
          __syncthreads();
        }
      }
    }
  };

  for (int i = 0; i < S_CNT; i++) {
    if (i == 0) layers(IC<4>{}, 0, true);
    else        layers(IC<1>{}, PP + i - 1, false);

    // ---- phase B: argmax finalize (+fin update by same thread) + fin-free logits ----
    {
      if (col == 0) {
        const int b = sq * 6;
        float bv = redv[b]; int bi = redi[b];
        for (int w = 1; w < 6; w++)
          if (redv[b + w] > bv || (redv[b + w] == bv && redi[b + w] < bi)) {
            bv = redv[b + w]; bi = redi[b + w];
          }
        if (bi == EOS_I) fin[sq] = 1;
      }
      if (col < NV) {
        float acc = 0.f;
        for (int j8 = 0; j8 < 48; j8 += 8) {
          W16 w[8];
          #pragma unroll
          for (int u = 0; u < 8; u++) w[u].v8 = Wlm8[(size_t)(j8 + u) * NV + col];
          #pragma unroll
          for (int u = 0; u < 8; u++) {
            W16 gv; gv.v8 = *(const h8*)&xh[sq][0][(j8 + u) * 8];
            #pragma unroll
            for (int r = 0; r < 4; r++) acc = fdot2(gv.h[r], w[u].h[r], acc);
          }
        }
        out[((size_t)(seq0 + sq) * S_CNT + i) * NV + col] = acc;
      }
      __syncthreads();
    }
  }
}

extern "C" void kernel_launch(void* const* d_in, const int* in_sizes, int n_in,
                              void* d_out, int out_size, void* d_ws, size_t ws_size,
                              hipStream_t stream) {
  const float* x     = (const float*)d_in[0];
  // d_in[1] = target (unused)
  const float* Wproj = (const float*)d_in[2];
  const float* an    = (const float*)d_in[3];
  const float* Wq    = (const float*)d_in[4];
  const float* Wk    = (const float*)d_in[5];
  const float* Wv    = (const float*)d_in[6];
  const float* Wo    = (const float*)d_in[7];
  const float* fn    = (const float*)d_in[8];
  const float* W1    = (const float*)d_in[9];
  const float* W2    = (const float*)d_in[10];
  const float* Wlm   = (const float*)d_in[11];
  float* out = (float*)d_out;
  (void)ws_size; (void)in_sizes; (void)n_in; (void)out_size;

  // ---- carve d_ws: h8-packed weights (gamma folded into Wq/Wk/Wv/W1), then f16 KV ----
  h8* w = (h8*)d_ws;
  const int n_proj = (H_IN / 8) * (PP * BH);
  const int n_qkv  = NL * (BH / 8) * BH * 3;   // fused interleaved QKV
  const int n_qkvo = NL * (BH / 8) * BH;
  const int n_w1   = NL * (BH / 8) * (4 * BH);
  const int n_w2   = NL * (4 * BH / 8) * BH;
  const int n_lm   = (BH / 8) * NV;
  h8* Wproj_p = w;  w += n_proj;
  h8* Wqkv_p  = w;  w += n_qkv;
  h8* Wo_p    = w;  w += n_qkvo;
  h8* W1_p    = w;  w += n_w1;
  h8* W2_p    = w;  w += n_w2;
  h8* Wlm_p   = w;  w += n_lm;
  const size_t kv_elems = (size_t)NSEQ * NL * TT * BH;
  _Float16* kbuf = (_Float16*)w;
  _Float16* vbuf = kbuf + kv_elems;

  auto pack = [&](const float* src, const float* g, h8* dst, int R, int C,
                  int stride3, int off3) {
    dim3 grid((C + 255) / 256, R / 8);
    pack8_kernel<<<grid, 256, 0, stream>>>(src, g, dst, C, stride3, off3);
  };
  pack(Wproj, nullptr, Wproj_p, H_IN,        PP * BH, 1, 0);
  pack(Wq,    an,      Wqkv_p,  NL * BH,     BH,      3, 0);
  pack(Wk,    an,      Wqkv_p,  NL * BH,     BH,      3, 1);
  pack(Wv,    an,      Wqkv_p,  NL * BH,     BH,      3, 2);
  pack(Wo,    nullptr, Wo_p,    NL * BH,     BH,      1, 0);
  pack(W1,    fn,      W1_p,    NL * BH,     4 * BH,  1, 0);
  pack(W2,    nullptr, W2_p,    NL * 4 * BH, BH,      1, 0);
  pack(Wlm,   nullptr, Wlm_p,   BH,          NV,      1, 0);

  decoder_kernel<<<NSEQ / 2, NTH, 0, stream>>>(
      x, Wproj_p, Wqkv_p, Wo_p, W1_p, W2_p, Wlm_p, out, kbuf, vbuf);
}